// Round 19
// baseline (122.283 us; speedup 1.0000x reference)
//
#include <hip/hip_runtime.h>
#include <math.h>
#include <stdint.h>

#define IMGS 64
#define HWDIM 512
#define KLEN 31
#define RAD 15
#define EPSV 1e-3f
#define MM_STRIDE 32   // ints per image slot (one 128B cache line each)
#define RSLOT 25       // 16B slots per raw row (24 data + 1 pad)

// ws layout (floats):
//   [0..31)     : separable weights s[i]  (kernel[i][j] = s_i*s_j)
//   [32..2080)  : per-image min/max int bits, 32-int stride
// d_out carries the pre-norm conv result, normalized in place by final_k.

typedef __attribute__((address_space(3))) uint8_t  lds_u8;
typedef const __attribute__((address_space(1))) uint8_t g_u8;

__global__ __launch_bounds__(128) void init_k(const float* __restrict__ gk,
                                              float* __restrict__ w,
                                              int* __restrict__ mm) {
    int t = threadIdx.x;
    if (t < KLEN) w[t] = sqrtf(gk[t * KLEN + t]);   // diag of s_i*s_j = s_i^2
    if (t < IMGS) { mm[t * MM_STRIDE] = 0x7F800000; mm[t * MM_STRIDE + 1] = 0; }
}

// Wave-autonomous fused separable conv: ONE WAVE per block, NO barriers.
// 64x32 output tile; raw 62x25-slot LDS region private to the wave.
// DMA stage -> per-wave vmcnt(0) -> in-place hconv (row-local, lockstep
// safe, per-wave DS ordering) -> per-lane-column vconv -> stores + minmax.
template <bool EDGE>
__device__ __forceinline__ void conv_body(const float* __restrict__ attn,
                                          float* __restrict__ out,
                                          const float* __restrict__ wg,
                                          int* __restrict__ mm,
                                          int img, int x0, int y0,
                                          float* __restrict__ raw) {
    const int lane = threadIdx.x;                // 0..63
    const float* src = attn + ((size_t)img << 18);
    const int gbq = (x0 >> 2) - 4;               // abs f4-group of slot 0

    // ---- DMA stage: 1550 slots (62 rows x 25) in 25 wave-instrs ----
#pragma unroll
    for (int i = 0; i < 25; ++i) {
        const int idx = (i << 6) + lane;
        int r = idx / 25;                        // magic-mul const div
        r = r > 61 ? 61 : r;                     // tail -> dup (pad slots)
        int s = idx - r * 25;
        s = s > 24 ? 24 : s;
        if (s == 24) s = 23;                     // row-pad slot: dup load
        int y = y0 - RAD + r;
        y = y < 0 ? 0 : (y > HWDIM - 1 ? HWDIM - 1 : y);
        int g = gbq + s;
        if (EDGE) g = g < 0 ? 0 : (g > 127 ? 127 : g);
        const float* gp = src + ((size_t)y << 9) + (g << 2);
        __builtin_amdgcn_global_load_lds((g_u8*)gp, (lds_u8*)&raw[idx << 2],
                                         16, 0, 0);
    }
    __builtin_amdgcn_sched_barrier(0);
    asm volatile("s_waitcnt vmcnt(0)" ::: "memory");   // per-wave, NOT a barrier
    __builtin_amdgcn_sched_barrier(0);

    // ---- in-place hconv: 4 rounds x (16 rows x 4 quarters) ----
#pragma unroll
    for (int rnd = 0; rnd < 4; ++rnd) {
        const int r = (rnd << 4) + (lane >> 2);
        const int q = lane & 3;
        if (r < 62) {
            const float* rb = &raw[(r * RSLOT + (q << 2)) << 2];
            float4 bv[12];
#pragma unroll
            for (int m = 0; m < 12; ++m) bv[m] = *(const float4*)(rb + (m << 2));
            const int y = y0 - RAD + r;
            const bool vy = (unsigned)y < (unsigned)HWDIM;
            const int gb = gbq + (q << 2);
            float vv[48];
#pragma unroll
            for (int m = 0; m < 12; ++m) {
                const bool vx = !EDGE || ((unsigned)(gb + m) < 128u);
                vv[4 * m + 0] = vx ? fminf(fmaxf(bv[m].x, 0.f), 1.f) : 0.f; // med3
                vv[4 * m + 1] = vx ? fminf(fmaxf(bv[m].y, 0.f), 1.f) : 0.f;
                vv[4 * m + 2] = vx ? fminf(fmaxf(bv[m].z, 0.f), 1.f) : 0.f;
                vv[4 * m + 3] = vx ? fminf(fmaxf(bv[m].w, 0.f), 1.f) : 0.f;
            }
            float* dst = &raw[(r * RSLOT + 4 + (q << 2)) << 2];
#pragma unroll
            for (int d = 0; d < 4; ++d) {
                float4 o;
                float* op = &o.x;
#pragma unroll
                for (int s2 = 0; s2 < 4; ++s2) {
                    const int oc = (d << 2) + s2;
                    float a = 0.f;
#pragma unroll
                    for (int k = 0; k < KLEN; ++k) a += vv[oc + 1 + k] * wg[k];
                    op[s2] = a;
                }
                if (!vy) o = make_float4(0.f, 0.f, 0.f, 0.f);
                *(float4*)(dst + (d << 2)) = o;
            }
        }
    }
    // per-wave DS ordering + C aliasing keep hconv writes before vconv reads.

    // ---- vconv: lane owns column x0+lane; 62 b32 reads -> 32 outputs ----
    float win[62];
#pragma unroll
    for (int k = 0; k < 62; ++k)
        win[k] = raw[k * (RSLOT * 4) + 16 + lane];
    float* dst = out + ((size_t)img << 18) + ((size_t)y0 << 9) + x0 + lane;
    float lmin = INFINITY, lmax = -INFINITY;
#pragma unroll
    for (int i = 0; i < 32; ++i) {
        float a = 0.f;
#pragma unroll
        for (int k = 0; k < KLEN; ++k) a += win[i + k] * wg[k];
        dst[(size_t)i << 9] = a;
        lmin = fminf(lmin, a);
        lmax = fmaxf(lmax, a);
    }
    // wave butterfly -> one atomic pair per wave (values >= 0 -> int order)
#pragma unroll
    for (int off = 1; off < 64; off <<= 1) {
        lmin = fminf(lmin, __shfl_xor(lmin, off, 64));
        lmax = fmaxf(lmax, __shfl_xor(lmax, off, 64));
    }
    if (lane == 0) {
        atomicMin(&mm[img * MM_STRIDE], __float_as_int(lmin));
        atomicMax(&mm[img * MM_STRIDE + 1], __float_as_int(lmax));
    }
}

__global__ __launch_bounds__(64) void conv_k(const float* __restrict__ attn,
                                             float* __restrict__ out,
                                             const float* __restrict__ wg,
                                             int* __restrict__ mm) {
    __shared__ float raw[1600 * 4];              // 25.6 KB -> 6 waves/CU
    // XCD swizzle: XCD k (bid&7) gets 1024 contiguous work items = 8 whole
    // images -> halo re-reads stay in that XCD's L2.
    const int b   = blockIdx.x;
    const int sw  = ((b & 7) << 10) | (b >> 3);
    const int img = sw >> 7;                     // 128 tiles per image
    const int s   = sw & 127;
    const int by  = s >> 3;                      // 0..15 (32-row bands)
    const int bx  = s & 7;
    const int x0 = bx << 6;
    const int y0 = by << 5;
    if (bx == 0 || bx == 7)
        conv_body<true>(attn, out, wg, mm, img, x0, y0, raw);
    else
        conv_body<false>(attn, out, wg, mm, img, x0, y0, raw);
}

// out = max((out - mn) / max(mx - mn, eps), clip(attn,0,1)), in place.
__global__ __launch_bounds__(256) void final_k(const float* __restrict__ attn,
                                               float* __restrict__ out,
                                               const int* __restrict__ mm) {
    const int img = blockIdx.x >> 6;             // 64 blocks of 4096 elems/image
    const float mn = __int_as_float(mm[img * MM_STRIDE]);
    const float mx = __int_as_float(mm[img * MM_STRIDE + 1]);
    const float inv = 1.0f / fmaxf(mx - mn, EPSV);
    const size_t base0 = ((size_t)blockIdx.x << 12) + ((size_t)threadIdx.x << 2);
#pragma unroll
    for (int h = 0; h < 4; ++h) {
        const size_t base = base0 + (size_t)h * 1024;
        float4 s = *(const float4*)(out + base);
        float4 a = *(const float4*)(attn + base);
        float4 o;
        o.x = fmaxf((s.x - mn) * inv, fminf(fmaxf(a.x, 0.f), 1.f));
        o.y = fmaxf((s.y - mn) * inv, fminf(fmaxf(a.y, 0.f), 1.f));
        o.z = fmaxf((s.z - mn) * inv, fminf(fmaxf(a.z, 0.f), 1.f));
        o.w = fmaxf((s.w - mn) * inv, fminf(fmaxf(a.w, 0.f), 1.f));
        *(float4*)(out + base) = o;
    }
}

extern "C" void kernel_launch(void* const* d_in, const int* in_sizes, int n_in,
                              void* d_out, int out_size, void* d_ws, size_t ws_size,
                              hipStream_t stream) {
    const float* attn = (const float*)d_in[0];
    const float* gk   = (const float*)d_in[1];
    float* out  = (float*)d_out;
    float* wsf  = (float*)d_ws;
    float* w1d  = wsf;
    int*   mm   = (int*)(wsf + 32);

    init_k<<<1, 128, 0, stream>>>(gk, w1d, mm);
    conv_k<<<IMGS * 128, 64, 0, stream>>>(attn, out, w1d, mm);
    final_k<<<IMGS * HWDIM * HWDIM / 4096, 256, 0, stream>>>(attn, out, mm);
}

// Round 21
// 80.463 us; speedup vs baseline: 1.5197x; 1.5197x over previous
//
#include <hip/hip_runtime.h>
#include <math.h>

#define IMGS 64
#define HWDIM 512
#define KLEN 31
#define RAD 15
#define EPSV 1e-3f
#define MM_STRIDE 32   // ints per image slot (one 128B cache line each)
#define ISTR 68        // inter row stride (floats): 68 == 4 (mod 32)

// ws layout (floats):
//   [0..31)     : separable weights s[i]  (kernel[i][j] = s_i*s_j)
//   [32..2080)  : per-image min/max int bits, 32-int stride
// d_out carries the pre-norm conv result, normalized in place by final_k.

__global__ __launch_bounds__(128) void init_k(const float* __restrict__ gk,
                                              float* __restrict__ w,
                                              int* __restrict__ mm) {
    int t = threadIdx.x;
    if (t < KLEN) w[t] = sqrtf(gk[t * KLEN + t]);   // diag of s_i*s_j = s_i^2
    if (t < IMGS) { mm[t * MM_STRIDE] = 0x7F800000; mm[t * MM_STRIDE + 1] = 0; }
}

// ---- phase A helpers: item = (row r 0..93, quarter q 0..3) -> 16 h-outputs ----
template <bool EDGE>
__device__ __forceinline__ void loadA(int i, const float* __restrict__ src,
                                      int x0, int y0, float4* __restrict__ b) {
    const int r = i >> 2, q = i & 3;
    int y = y0 - RAD + r;
    if (EDGE) y = y < 0 ? 0 : (y > HWDIM - 1 ? HWDIM - 1 : y);
    const float4* row = (const float4*)(src + ((size_t)y << 9));
    const int gb = (x0 >> 2) + (q << 2) - 4;
#pragma unroll
    for (int m = 0; m < 12; ++m) {
        int g = gb + m;
        if (EDGE) g = g < 0 ? 0 : (g > 127 ? 127 : g);
        b[m] = row[g];
    }
}

template <bool EDGE>
__device__ __forceinline__ void compA(int i, int x0, int y0,
                                      const float* __restrict__ wg,
                                      float* __restrict__ inter,
                                      const float4* __restrict__ b) {
    const int r = i >> 2, q = i & 3;
    const int y = y0 - RAD + r;
    const int gb = (x0 >> 2) + (q << 2) - 4;
    const bool vy = !EDGE || ((unsigned)y < HWDIM);
    float vv[48];
#pragma unroll
    for (int m = 0; m < 12; ++m) {
        const bool vx = !EDGE || (vy && ((unsigned)(gb + m) < 128u));
        vv[4 * m + 0] = vx ? fminf(fmaxf(b[m].x, 0.f), 1.f) : 0.f;  // v_med3
        vv[4 * m + 1] = vx ? fminf(fmaxf(b[m].y, 0.f), 1.f) : 0.f;
        vv[4 * m + 2] = vx ? fminf(fmaxf(b[m].z, 0.f), 1.f) : 0.f;
        vv[4 * m + 3] = vx ? fminf(fmaxf(b[m].w, 0.f), 1.f) : 0.f;
    }
    float* dst = &inter[r * ISTR + (q << 4)];
#pragma unroll
    for (int d = 0; d < 4; ++d) {
        float4 o;
        float* op = &o.x;
#pragma unroll
        for (int s = 0; s < 4; ++s) {
            const int oc = (d << 2) + s;
            float a = 0.f;
#pragma unroll
            for (int k = 0; k < KLEN; ++k) a += vv[oc + 1 + k] * wg[k];
            op[s] = a;
        }
        *(float4*)(dst + (d << 2)) = o;
    }
}

// Fused separable 31x31 conv per 64x64 output tile.
// Phase A: hconv, 16 outputs/thread-item, both items' loads issued up front.
// Phase B: vconv from LDS -> pre-norm out + per-image min/max atomics.
template <bool EDGE>
__device__ __forceinline__ void conv_body(const float* __restrict__ attn,
                                          float* __restrict__ out,
                                          const float* __restrict__ wg,
                                          int* __restrict__ mm,
                                          int img, int x0, int y0,
                                          float* __restrict__ inter,
                                          float* __restrict__ sred) {
    const int t = threadIdx.x;
    const float* src = attn + ((size_t)img << 18);

    {   // ---- phase A: 376 items; thread t owns item t and (t<120) 256+t ----
        float4 bA[12], bB[12];
        const bool hasB = t < 120;
        loadA<EDGE>(t, src, x0, y0, bA);
        if (hasB) loadA<EDGE>(256 + t, src, x0, y0, bB);
        compA<EDGE>(t, x0, y0, wg, inter, bA);
        if (hasB) compA<EDGE>(256 + t, x0, y0, wg, inter, bB);
    }
    __syncthreads();

    // ---- phase B: vconv, each thread owns a 4-col x 4-row patch ----
    const int tx = t & 15;
    const int ty = t >> 4;
    float4 acc[4];
#pragma unroll
    for (int i = 0; i < 4; ++i) acc[i] = make_float4(0.f, 0.f, 0.f, 0.f);
#pragma unroll
    for (int k = 0; k < 34; ++k) {
        const float4 v = *(const float4*)&inter[((ty << 2) + k) * ISTR + (tx << 2)];
#pragma unroll
        for (int i = 0; i < 4; ++i) {
            const int j = k - i;                 // weight index, compile-time
            if (j >= 0 && j < KLEN) {
                const float w = wg[j];
                acc[i].x += v.x * w;
                acc[i].y += v.y * w;
                acc[i].z += v.z * w;
                acc[i].w += v.w * w;
            }
        }
    }
    float* dst = out + ((size_t)img << 18);
    float lmin = INFINITY, lmax = -INFINITY;
#pragma unroll
    for (int i = 0; i < 4; ++i) {
        *(float4*)&dst[(size_t)(y0 + (ty << 2) + i) * HWDIM + x0 + (tx << 2)] = acc[i];
        lmin = fminf(lmin, fminf(fminf(acc[i].x, acc[i].y), fminf(acc[i].z, acc[i].w)));
        lmax = fmaxf(lmax, fmaxf(fmaxf(acc[i].x, acc[i].y), fmaxf(acc[i].z, acc[i].w)));
    }
    // wave butterfly -> block LDS reduce -> one atomic pair per block
#pragma unroll
    for (int off = 1; off < 64; off <<= 1) {
        lmin = fminf(lmin, __shfl_xor(lmin, off, 64));
        lmax = fmaxf(lmax, __shfl_xor(lmax, off, 64));
    }
    const int lane = t & 63, wid = t >> 6;
    if (lane == 0) { sred[wid] = lmin; sred[4 + wid] = lmax; }
    __syncthreads();
    if (t == 0) {
        float bmin = fminf(fminf(sred[0], sred[1]), fminf(sred[2], sred[3]));
        float bmax = fmaxf(fmaxf(sred[4], sred[5]), fmaxf(sred[6], sred[7]));
        // all values >= 0 -> float ordering == int-bits ordering
        atomicMin(&mm[img * MM_STRIDE], __float_as_int(bmin));
        atomicMax(&mm[img * MM_STRIDE + 1], __float_as_int(bmax));
    }
}

__global__ __launch_bounds__(256, 2) void conv_k(const float* __restrict__ attn,
                                                 float* __restrict__ out,
                                                 const float* __restrict__ wg,
                                                 int* __restrict__ mm) {
    __shared__ float inter[94 * ISTR];           // 25.0 KB
    __shared__ float sred[8];
    // XCD swizzle: XCD k (bid&7) gets 512 contiguous work items = 8 whole
    // images -> halo re-reads stay in that XCD's L2.
    const int sw  = ((blockIdx.x & 7) << 9) + (blockIdx.x >> 3);
    const int img = sw >> 6;
    const int by  = (sw >> 3) & 7;
    const int bx  = sw & 7;
    const int x0 = bx << 6;
    const int y0 = by << 6;
    if (bx == 0 || bx == 7 || by == 0 || by == 7)
        conv_body<true>(attn, out, wg, mm, img, x0, y0, inter, sred);
    else
        conv_body<false>(attn, out, wg, mm, img, x0, y0, inter, sred);
}

// out = max((out - mn) / max(mx - mn, eps), clip(attn,0,1)), in place.
// XCD-aligned: XCD k (bid&7) normalizes images 8k..8k+7 — the same images
// conv_k's XCD k just wrote, so pre-norm reads hit the local L2 partition.
__global__ __launch_bounds__(256) void final_k(const float* __restrict__ attn,
                                               float* __restrict__ out,
                                               const int* __restrict__ mm) {
    const int b   = blockIdx.x;
    const int xcd = b & 7;
    const int idx = b >> 3;                      // 0..511
    const int img = (xcd << 3) | (idx >> 6);     // 8 images per XCD
    const int blk = idx & 63;                    // 64 blocks of 4096 elems/image
    const float mn = __int_as_float(mm[img * MM_STRIDE]);
    const float mx = __int_as_float(mm[img * MM_STRIDE + 1]);
    const float inv = 1.0f / fmaxf(mx - mn, EPSV);
    const size_t base0 = ((size_t)img << 18) + ((size_t)blk << 12)
                       + ((size_t)threadIdx.x << 2);
#pragma unroll
    for (int h = 0; h < 4; ++h) {
        const size_t base = base0 + (size_t)h * 1024;
        float4 s = *(const float4*)(out + base);
        float4 a = *(const float4*)(attn + base);
        float4 o;
        o.x = fmaxf((s.x - mn) * inv, fminf(fmaxf(a.x, 0.f), 1.f));
        o.y = fmaxf((s.y - mn) * inv, fminf(fmaxf(a.y, 0.f), 1.f));
        o.z = fmaxf((s.z - mn) * inv, fminf(fmaxf(a.z, 0.f), 1.f));
        o.w = fmaxf((s.w - mn) * inv, fminf(fmaxf(a.w, 0.f), 1.f));
        *(float4*)(out + base) = o;
    }
}

extern "C" void kernel_launch(void* const* d_in, const int* in_sizes, int n_in,
                              void* d_out, int out_size, void* d_ws, size_t ws_size,
                              hipStream_t stream) {
    const float* attn = (const float*)d_in[0];
    const float* gk   = (const float*)d_in[1];
    float* out  = (float*)d_out;
    float* wsf  = (float*)d_ws;
    float* w1d  = wsf;
    int*   mm   = (int*)(wsf + 32);

    init_k<<<1, 128, 0, stream>>>(gk, w1d, mm);
    conv_k<<<4096, 256, 0, stream>>>(attn, out, w1d, mm);
    final_k<<<IMGS * HWDIM * HWDIM / 4096, 256, 0, stream>>>(attn, out, mm);
}